// Round 2
// baseline (1862.122 us; speedup 1.0000x reference)
//
#include <hip/hip_runtime.h>
#include <math.h>

#define NN   100000
#define HH   128
#define EXTD 768
#define EE   1600000
#define LNEPS 1e-5f

__device__ __forceinline__ int uni(int x) { return __builtin_amdgcn_readfirstlane(x); }

// ---------------- CSR build ----------------

__global__ void k_init(int* __restrict__ deg, int* __restrict__ counter) {
    int i = blockIdx.x * 256 + threadIdx.x;
    if (i < NN) deg[i] = 1;            // self loop contributes 1 to degree
    if (i == 0) *counter = 0;
}

__global__ void k_count(const int* __restrict__ dst, int* __restrict__ deg) {
    int e = blockIdx.x * 256 + threadIdx.x;
    if (e < EE) atomicAdd(&deg[dst[e]], 1);
}

__global__ void k_offsets(const int* __restrict__ deg, float* __restrict__ dinv,
                          int* __restrict__ rowstart, int* __restrict__ cursor,
                          int* __restrict__ counter) {
    int i = blockIdx.x * 256 + threadIdx.x;
    if (i < NN) {
        int d = deg[i];
        dinv[i] = rsqrtf((float)d);
        int rs = atomicAdd(counter, d - 1);   // in-degree excluding self loop
        rowstart[i] = rs;
        cursor[i]   = rs;
    }
}

__global__ void k_fill(const int* __restrict__ src, const int* __restrict__ dst,
                       int* __restrict__ cursor, int* __restrict__ col) {
    int e = blockIdx.x * 256 + threadIdx.x;
    if (e < EE) {
        int d = dst[e];
        int p = atomicAdd(&cursor[d], 1);
        col[p] = src[e];
    }
}

// ---------------- GEMM: C[N x 128] = A[N x K] @ W[K x 128] (+bias) (+LN+ReLU) ----------------
// Layout: block = 128 rows x 128 cols, 512 threads = 8 waves.
// wave w: row-group (w&1)*64, col-slice (w>>1)*32. lane = row within group.
// A staged in LDS (stride 33 -> conflict-free lane=row reads, 1 ds_read_b32/k).
// W read at wave-uniform addresses from const __restrict__ global -> s_load,
// FMA consumes the weight as the SGPR operand. No LDS traffic for W at all.

template<int LNRELU, int CONCAT>
__global__ __launch_bounds__(512)
void k_gemm(const float* __restrict__ A0, const float* __restrict__ A1,
            const float* __restrict__ W,  const float* __restrict__ bias,
            const float* __restrict__ lng, const float* __restrict__ lnb,
            float* __restrict__ C, int K)
{
    __shared__ float As[128 * 33];

    const int tid  = threadIdx.x;
    const int w    = tid >> 6;
    const int lane = tid & 63;
    const int rowg = w & 1;
    const int colg = w >> 1;                    // 0..3
    const int c0   = uni(colg * 32);            // wave-uniform column base
    const int rloc = rowg * 64 + lane;          // 0..127 local row
    const int grow = blockIdx.x * 128 + rloc;

    // A-staging mapping: thread loads 2 float4 of row srow
    const int srow  = tid >> 2;                 // 0..127
    const int sj    = (tid & 3) * 4;            // float offset within 32-chunk (and +16)
    const int gsrow = blockIdx.x * 128 + srow;

    float acc[32];
#pragma unroll
    for (int j = 0; j < 32; ++j) acc[j] = 0.f;

    for (int k0 = 0; k0 < K; k0 += 32) {
        float4 va0 = make_float4(0.f, 0.f, 0.f, 0.f);
        float4 va1 = make_float4(0.f, 0.f, 0.f, 0.f);
        if (gsrow < NN) {
            const float* ap;
            if (CONCAT) {
                ap = (k0 < HH) ? (A0 + (size_t)gsrow * HH + k0)
                               : (A1 + (size_t)gsrow * HH + (k0 - HH));
            } else {
                ap = A0 + (size_t)gsrow * K + k0;
            }
            va0 = *(const float4*)(ap + sj);
            va1 = *(const float4*)(ap + sj + 16);
        }
        __syncthreads();
        {
            float* s = &As[srow * 33 + sj];
            s[0] = va0.x; s[1] = va0.y; s[2] = va0.z; s[3] = va0.w;
            s[16] = va1.x; s[17] = va1.y; s[18] = va1.z; s[19] = va1.w;
        }
        __syncthreads();

#pragma unroll
        for (int k = 0; k < 32; ++k) {
            const float a = As[rloc * 33 + k];
            const float* wrow = W + (size_t)(k0 + k) * 128 + c0;   // wave-uniform
#pragma unroll
            for (int j = 0; j < 32; ++j)
                acc[j] = fmaf(a, wrow[j], acc[j]);
        }
    }

    if (bias != nullptr) {
#pragma unroll
        for (int j = 0; j < 32; ++j) acc[j] += bias[c0 + j];      // scalar loads
    }

    if constexpr (LNRELU) {
        __shared__ float r1[128 * 5];
        __shared__ float r2[128 * 5];
        float s1 = 0.f, s2 = 0.f;
#pragma unroll
        for (int j = 0; j < 32; ++j) { s1 += acc[j]; s2 = fmaf(acc[j], acc[j], s2); }
        r1[rloc * 5 + colg] = s1;
        r2[rloc * 5 + colg] = s2;
        __syncthreads();
        const float a = r1[rloc * 5 + 0] + r1[rloc * 5 + 1] + r1[rloc * 5 + 2] + r1[rloc * 5 + 3];
        const float b = r2[rloc * 5 + 0] + r2[rloc * 5 + 1] + r2[rloc * 5 + 2] + r2[rloc * 5 + 3];
        const float mu  = a * (1.0f / HH);
        const float var = fmaf(-mu, mu, b * (1.0f / HH));
        const float rsd = rsqrtf(var + LNEPS);
#pragma unroll
        for (int j = 0; j < 32; ++j) {
            float v = (acc[j] - mu) * rsd;
            v = fmaf(v, lng[c0 + j], lnb[c0 + j]);                // scalar loads
            acc[j] = fmaxf(v, 0.f);
        }
    }

    if (grow < NN) {
        float* cp = C + (size_t)grow * 128 + c0;
#pragma unroll
        for (int q = 0; q < 8; ++q) {
            *(float4*)(cp + q * 4) =
                make_float4(acc[q * 4], acc[q * 4 + 1], acc[q * 4 + 2], acc[q * 4 + 3]);
        }
    }
}

// ---------------- SpMM: out[d] = dinv[d]*(sum_e dinv[src]*Y[src] + dinv[d]*Y[d]) + bias ----------------
// One wave per destination node; lane owns 2 channels. Edge loop unrolled x4
// so 4 independent 512B row-gathers are in flight per wave.

__global__ __launch_bounds__(256)
void k_spmm(const float* __restrict__ Y, const int* __restrict__ col,
            const int* __restrict__ rs, const int* __restrict__ re,
            const float* __restrict__ dinv, const float* __restrict__ bias,
            float* __restrict__ out, int dorelu)
{
    int gid  = blockIdx.x * blockDim.x + threadIdx.x;
    int node = gid >> 6;
    int lane = threadIdx.x & 63;
    if (node >= NN) return;

    const int beg = rs[node];
    const int end = re[node];
    const float di = dinv[node];
    const size_t lofs = (size_t)(lane * 2);

    float ax, ay;
    {   // self loop: norm = di*di (outer di applied at the end)
        const float2 v = *(const float2*)(Y + (size_t)node * HH + lofs);
        ax = di * v.x;
        ay = di * v.y;
    }

    int e = beg;
    const int e4 = beg + ((end - beg) & ~3);
    for (; e < e4; e += 4) {
        const int s0 = col[e + 0];
        const int s1 = col[e + 1];
        const int s2 = col[e + 2];
        const int s3 = col[e + 3];
        const float w0 = dinv[s0];
        const float w1 = dinv[s1];
        const float w2 = dinv[s2];
        const float w3 = dinv[s3];
        const float2 v0 = *(const float2*)(Y + (size_t)s0 * HH + lofs);
        const float2 v1 = *(const float2*)(Y + (size_t)s1 * HH + lofs);
        const float2 v2 = *(const float2*)(Y + (size_t)s2 * HH + lofs);
        const float2 v3 = *(const float2*)(Y + (size_t)s3 * HH + lofs);
        ax = fmaf(w0, v0.x, ax); ay = fmaf(w0, v0.y, ay);
        ax = fmaf(w1, v1.x, ax); ay = fmaf(w1, v1.y, ay);
        ax = fmaf(w2, v2.x, ax); ay = fmaf(w2, v2.y, ay);
        ax = fmaf(w3, v3.x, ax); ay = fmaf(w3, v3.y, ay);
    }
    for (; e < end; ++e) {
        const int s = col[e];
        const float ww = dinv[s];
        const float2 v = *(const float2*)(Y + (size_t)s * HH + lofs);
        ax = fmaf(ww, v.x, ax);
        ay = fmaf(ww, v.y, ay);
    }

    float ox = fmaf(di, ax, bias[lane * 2]);
    float oy = fmaf(di, ay, bias[lane * 2 + 1]);
    if (dorelu) { ox = fmaxf(ox, 0.f); oy = fmaxf(oy, 0.f); }
    float2 o; o.x = ox; o.y = oy;
    *(float2*)(out + (size_t)node * HH + lofs) = o;
}

// ---------------- launch ----------------

extern "C" void kernel_launch(void* const* d_in, const int* in_sizes, int n_in,
                              void* d_out, int out_size, void* d_ws, size_t ws_size,
                              hipStream_t stream)
{
    const int*   ei    = (const int*)d_in[0];
    const float* ext   = (const float*)d_in[1];
    const float* emb   = (const float*)d_in[2];
    const float* encW  = (const float*)d_in[3];
    const float* encB  = (const float*)d_in[4];
    const float* lng   = (const float*)d_in[5];
    const float* lnb   = (const float*)d_in[6];
    const float* projW = (const float*)d_in[7];
    const float* projB = (const float*)d_in[8];
    const float* W0    = (const float*)d_in[9];
    const float* b0    = (const float*)d_in[10];
    const float* W1    = (const float*)d_in[11];
    const float* b1    = (const float*)d_in[12];
    const float* W2    = (const float*)d_in[13];
    const float* b2    = (const float*)d_in[14];

    const int* srcI = ei;        // edge_index[0]
    const int* dstI = ei + EE;   // edge_index[1]

    char* w = (char*)d_ws;
    size_t off = 0;
    auto alloc = [&](size_t bytes) -> void* {
        void* p = w + off;
        off += (bytes + 255) & ~(size_t)255;
        return p;
    };
    int*   deg      = (int*)alloc((size_t)NN * 4);
    float* dinv     = (float*)alloc((size_t)NN * 4);
    int*   rowstart = (int*)alloc((size_t)NN * 4);
    int*   cursor   = (int*)alloc((size_t)NN * 4);
    int*   counter  = (int*)alloc(256);
    int*   col      = (int*)alloc((size_t)EE * 4);
    float* bufA     = (float*)alloc((size_t)NN * HH * 4);
    float* bufB     = (float*)alloc((size_t)NN * HH * 4);

    const int gN = (NN + 255) / 256;
    const int gE = (EE + 255) / 256;
    const int gG = (NN + 127) / 128;   // 128 rows per block
    const int gS = (NN + 3) / 4;       // 4 waves (nodes) per 256-thread block

    k_init   <<<gN, 256, 0, stream>>>(deg, counter);
    k_count  <<<gE, 256, 0, stream>>>(dstI, deg);
    k_offsets<<<gN, 256, 0, stream>>>(deg, dinv, rowstart, cursor, counter);
    k_fill   <<<gE, 256, 0, stream>>>(srcI, dstI, cursor, col);

    // feat = relu(LN(ext @ encW + encB))            -> bufA
    k_gemm<1, 0><<<gG, 512, 0, stream>>>(ext, nullptr, encW, encB, lng, lnb, bufA, EXTD);
    // x = concat(emb, feat) @ projW + projB         -> bufB
    k_gemm<0, 1><<<gG, 512, 0, stream>>>(emb, bufA, projW, projB, nullptr, nullptr, bufB, 2 * HH);
    // y = x @ W0                                    -> bufA
    k_gemm<0, 0><<<gG, 512, 0, stream>>>(bufB, nullptr, W0, nullptr, nullptr, nullptr, bufA, HH);
    // x = relu(spmm(y) + b0)                        -> bufB
    k_spmm<<<gS, 256, 0, stream>>>(bufA, col, rowstart, cursor, dinv, b0, bufB, 1);
    // y = x @ W1                                    -> bufA
    k_gemm<0, 0><<<gG, 512, 0, stream>>>(bufB, nullptr, W1, nullptr, nullptr, nullptr, bufA, HH);
    // x = relu(spmm(y) + b1)                        -> bufB
    k_spmm<<<gS, 256, 0, stream>>>(bufA, col, rowstart, cursor, dinv, b1, bufB, 1);
    // y = x @ W2                                    -> bufA
    k_gemm<0, 0><<<gG, 512, 0, stream>>>(bufB, nullptr, W2, nullptr, nullptr, nullptr, bufA, HH);
    // out = spmm(y) + b2                            -> d_out
    k_spmm<<<gS, 256, 0, stream>>>(bufA, col, rowstart, cursor, dinv, b2, (float*)d_out, 0);
}

// Round 3
// 1488.032 us; speedup vs baseline: 1.2514x; 1.2514x over previous
//
#include <hip/hip_runtime.h>
#include <math.h>

#define NN   100000
#define HH   128
#define EXTD 768
#define EE   1600000
#define LNEPS 1e-5f

#define BK   32
#define LSTR 132   // LDS row stride (128 + 4 pad)

// ---------------- CSR build ----------------

__global__ void k_init(int* __restrict__ deg, int* __restrict__ counter) {
    int i = blockIdx.x * 256 + threadIdx.x;
    if (i < NN) deg[i] = 1;            // self loop contributes 1 to degree
    if (i == 0) *counter = 0;
}

__global__ void k_count(const int* __restrict__ dst, int* __restrict__ deg) {
    int e = blockIdx.x * 256 + threadIdx.x;
    if (e < EE) atomicAdd(&deg[dst[e]], 1);
}

__global__ void k_offsets(const int* __restrict__ deg, float* __restrict__ dinv,
                          int* __restrict__ rowstart, int* __restrict__ cursor,
                          int* __restrict__ counter) {
    int i = blockIdx.x * 256 + threadIdx.x;
    if (i < NN) {
        int d = deg[i];
        dinv[i] = rsqrtf((float)d);
        int rs = atomicAdd(counter, d - 1);   // in-degree excluding self loop
        rowstart[i] = rs;
        cursor[i]   = rs;
    }
}

__global__ void k_fill(const int* __restrict__ src, const int* __restrict__ dst,
                       int* __restrict__ cursor, int* __restrict__ col) {
    int e = blockIdx.x * 256 + threadIdx.x;
    if (e < EE) {
        int d = dst[e];
        int p = atomicAdd(&cursor[d], 1);
        col[p] = src[e];
    }
}

// ---------------- GEMM: C[N x 128] = A[N x K] @ W[K x 128] (+bias)(+LN+ReLU)(+rowscale) ----
// 128x128 block, 256 threads, 8x8 per-thread tile.
// A-frag LDS reads are 16-lane broadcasts (depend on ty only); B-frag reads are
// 4-lane broadcasts -> unique LDS bytes/wave/k is small -> VALU-bound.

template<int LNRELU, int CONCAT, int ROWSCALE>
__global__ __launch_bounds__(256, 4)
void k_gemm(const float* __restrict__ A0, const float* __restrict__ A1,
            const float* __restrict__ W,  const float* __restrict__ bias,
            const float* __restrict__ lng, const float* __restrict__ lnb,
            const float* __restrict__ rowscale,
            float* __restrict__ C, int K)
{
    __shared__ float As[BK * LSTR];   // [k][row]
    __shared__ float Bs[BK * LSTR];   // [k][col]

    const int tid  = threadIdx.x;
    const int tx   = tid & 15;         // col group (8 cols)
    const int ty   = tid >> 4;         // row group (8 rows)
    const int row0 = blockIdx.x * 128;

    // A staging: thread covers row ar, 16 consecutive k-floats starting at ah
    const int ar    = tid >> 1;          // 0..127
    const int ah    = (tid & 1) * 16;    // 0 or 16
    const int garow = row0 + ar;

    // B staging: thread loads 4 float4: k rows bkr, bkr+8, bkr+16, bkr+24; cols bc..bc+3
    const int bkr = tid >> 5;            // 0..7
    const int bc  = (tid & 31) * 4;      // 0..124

    float acc[8][8];
#pragma unroll
    for (int i = 0; i < 8; ++i)
#pragma unroll
        for (int j = 0; j < 8; ++j) acc[i][j] = 0.f;

    for (int k0 = 0; k0 < K; k0 += BK) {
        float4 a_ld[2] = {make_float4(0.f,0.f,0.f,0.f), make_float4(0.f,0.f,0.f,0.f)};
        float4 a_ld2[2] = {make_float4(0.f,0.f,0.f,0.f), make_float4(0.f,0.f,0.f,0.f)};
        if (garow < NN) {
            const float* ap;
            if (CONCAT) {
                ap = (k0 < HH) ? (A0 + (size_t)garow * HH + k0)
                               : (A1 + (size_t)garow * HH + (k0 - HH));
            } else {
                ap = A0 + (size_t)garow * K + k0;
            }
            a_ld[0]  = *(const float4*)(ap + ah + 0);
            a_ld[1]  = *(const float4*)(ap + ah + 4);
            a_ld2[0] = *(const float4*)(ap + ah + 8);
            a_ld2[1] = *(const float4*)(ap + ah + 12);
        }
        float4 b_ld[4];
#pragma unroll
        for (int p = 0; p < 4; ++p)
            b_ld[p] = *(const float4*)(W + (size_t)(k0 + bkr + p * 8) * 128 + bc);

        __syncthreads();
        {
            const float av[16] = {a_ld[0].x, a_ld[0].y, a_ld[0].z, a_ld[0].w,
                                  a_ld[1].x, a_ld[1].y, a_ld[1].z, a_ld[1].w,
                                  a_ld2[0].x, a_ld2[0].y, a_ld2[0].z, a_ld2[0].w,
                                  a_ld2[1].x, a_ld2[1].y, a_ld2[1].z, a_ld2[1].w};
#pragma unroll
            for (int m = 0; m < 16; ++m)
                As[(ah + m) * LSTR + ar] = av[m];
#pragma unroll
            for (int p = 0; p < 4; ++p)
                *(float4*)&Bs[(bkr + p * 8) * LSTR + bc] = b_ld[p];
        }
        __syncthreads();

#pragma unroll 4
        for (int k = 0; k < BK; ++k) {
            const float4 a0 = *(const float4*)&As[k * LSTR + ty * 8];
            const float4 a1 = *(const float4*)&As[k * LSTR + ty * 8 + 4];
            const float4 b0 = *(const float4*)&Bs[k * LSTR + tx * 8];
            const float4 b1 = *(const float4*)&Bs[k * LSTR + tx * 8 + 4];
            const float av[8] = {a0.x, a0.y, a0.z, a0.w, a1.x, a1.y, a1.z, a1.w};
            const float bv[8] = {b0.x, b0.y, b0.z, b0.w, b1.x, b1.y, b1.z, b1.w};
#pragma unroll
            for (int i = 0; i < 8; ++i)
#pragma unroll
                for (int j = 0; j < 8; ++j)
                    acc[i][j] = fmaf(av[i], bv[j], acc[i][j]);
        }
    }

    const int c0 = tx * 8;

    if (bias != nullptr) {
        const float4 q0 = *(const float4*)&bias[c0];
        const float4 q1 = *(const float4*)&bias[c0 + 4];
        const float qb[8] = {q0.x, q0.y, q0.z, q0.w, q1.x, q1.y, q1.z, q1.w};
#pragma unroll
        for (int i = 0; i < 8; ++i)
#pragma unroll
            for (int j = 0; j < 8; ++j) acc[i][j] += qb[j];
    }

    if constexpr (LNRELU) {
        // per-row reduce across the 16 tx lanes (consecutive lanes, xor shuffles)
        const float4 g0 = *(const float4*)&lng[c0];
        const float4 g1 = *(const float4*)&lng[c0 + 4];
        const float4 h0 = *(const float4*)&lnb[c0];
        const float4 h1 = *(const float4*)&lnb[c0 + 4];
        const float gg[8] = {g0.x, g0.y, g0.z, g0.w, g1.x, g1.y, g1.z, g1.w};
        const float hh[8] = {h0.x, h0.y, h0.z, h0.w, h1.x, h1.y, h1.z, h1.w};
#pragma unroll
        for (int i = 0; i < 8; ++i) {
            float s1 = 0.f, s2 = 0.f;
#pragma unroll
            for (int j = 0; j < 8; ++j) { s1 += acc[i][j]; s2 = fmaf(acc[i][j], acc[i][j], s2); }
#pragma unroll
            for (int m = 1; m < 16; m <<= 1) {
                s1 += __shfl_xor(s1, m);
                s2 += __shfl_xor(s2, m);
            }
            const float mu  = s1 * (1.0f / HH);
            const float var = fmaf(-mu, mu, s2 * (1.0f / HH));
            const float rsd = rsqrtf(var + LNEPS);
#pragma unroll
            for (int j = 0; j < 8; ++j) {
                float v = (acc[i][j] - mu) * rsd;
                v = fmaf(v, gg[j], hh[j]);
                acc[i][j] = fmaxf(v, 0.f);
            }
        }
    }

    if constexpr (ROWSCALE) {
#pragma unroll
        for (int i = 0; i < 8; ++i) {
            const int r = row0 + ty * 8 + i;
            const float sc = (r < NN) ? rowscale[r] : 0.f;
#pragma unroll
            for (int j = 0; j < 8; ++j) acc[i][j] *= sc;
        }
    }

#pragma unroll
    for (int i = 0; i < 8; ++i) {
        const int r = row0 + ty * 8 + i;
        if (r < NN) {
            float* cp = C + (size_t)r * 128 + c0;
            *(float4*)(cp)     = make_float4(acc[i][0], acc[i][1], acc[i][2], acc[i][3]);
            *(float4*)(cp + 4) = make_float4(acc[i][4], acc[i][5], acc[i][6], acc[i][7]);
        }
    }
}

// ---------------- SpMM: out[d] = dinv[d]*(sum Z[src] + Z[d]) + bias, Z pre-scaled by dinv ----
// One wave per destination node; lane owns 2 channels. x8 unroll: 8 independent
// 512B row gathers in flight; col[] reads are wave-uniform (scalar path).

__global__ __launch_bounds__(256)
void k_spmm(const float* __restrict__ Z, const int* __restrict__ col,
            const int* __restrict__ rs, const int* __restrict__ re,
            const float* __restrict__ dinv, const float* __restrict__ bias,
            float* __restrict__ out, int dorelu)
{
    int gid  = blockIdx.x * blockDim.x + threadIdx.x;
    int node = gid >> 6;
    int lane = threadIdx.x & 63;
    if (node >= NN) return;

    const int beg = rs[node];
    const int end = re[node];
    const float di = dinv[node];
    const size_t lofs = (size_t)(lane * 2);

    float ax, ay;
    {   // self loop: Z[d] already = dinv[d]*Y[d]
        const float2 v = *(const float2*)(Z + (size_t)node * HH + lofs);
        ax = v.x;
        ay = v.y;
    }

    int e = beg;
    const int e8 = beg + ((end - beg) & ~7);
    for (; e < e8; e += 8) {
        int s[8];
#pragma unroll
        for (int q = 0; q < 8; ++q) s[q] = col[e + q];
        float2 v[8];
#pragma unroll
        for (int q = 0; q < 8; ++q)
            v[q] = *(const float2*)(Z + (size_t)s[q] * HH + lofs);
#pragma unroll
        for (int q = 0; q < 8; ++q) { ax += v[q].x; ay += v[q].y; }
    }
    for (; e < end; ++e) {
        const int s0 = col[e];
        const float2 v = *(const float2*)(Z + (size_t)s0 * HH + lofs);
        ax += v.x;
        ay += v.y;
    }

    float ox = fmaf(di, ax, bias[lane * 2]);
    float oy = fmaf(di, ay, bias[lane * 2 + 1]);
    if (dorelu) { ox = fmaxf(ox, 0.f); oy = fmaxf(oy, 0.f); }
    float2 o; o.x = ox; o.y = oy;
    *(float2*)(out + (size_t)node * HH + lofs) = o;
}

// ---------------- launch ----------------

extern "C" void kernel_launch(void* const* d_in, const int* in_sizes, int n_in,
                              void* d_out, int out_size, void* d_ws, size_t ws_size,
                              hipStream_t stream)
{
    const int*   ei    = (const int*)d_in[0];
    const float* ext   = (const float*)d_in[1];
    const float* emb   = (const float*)d_in[2];
    const float* encW  = (const float*)d_in[3];
    const float* encB  = (const float*)d_in[4];
    const float* lng   = (const float*)d_in[5];
    const float* lnb   = (const float*)d_in[6];
    const float* projW = (const float*)d_in[7];
    const float* projB = (const float*)d_in[8];
    const float* W0    = (const float*)d_in[9];
    const float* b0    = (const float*)d_in[10];
    const float* W1    = (const float*)d_in[11];
    const float* b1    = (const float*)d_in[12];
    const float* W2    = (const float*)d_in[13];
    const float* b2    = (const float*)d_in[14];

    const int* srcI = ei;        // edge_index[0]
    const int* dstI = ei + EE;   // edge_index[1]

    char* w = (char*)d_ws;
    size_t off = 0;
    auto alloc = [&](size_t bytes) -> void* {
        void* p = w + off;
        off += (bytes + 255) & ~(size_t)255;
        return p;
    };
    int*   deg      = (int*)alloc((size_t)NN * 4);
    float* dinv     = (float*)alloc((size_t)NN * 4);
    int*   rowstart = (int*)alloc((size_t)NN * 4);
    int*   cursor   = (int*)alloc((size_t)NN * 4);
    int*   counter  = (int*)alloc(256);
    int*   col      = (int*)alloc((size_t)EE * 4);
    float* bufA     = (float*)alloc((size_t)NN * HH * 4);
    float* bufB     = (float*)alloc((size_t)NN * HH * 4);

    const int gN = (NN + 255) / 256;
    const int gE = (EE + 255) / 256;
    const int gG = (NN + 127) / 128;   // 128 rows per block
    const int gS = (NN + 3) / 4;       // 4 waves (nodes) per 256-thread block

    k_init   <<<gN, 256, 0, stream>>>(deg, counter);
    k_count  <<<gE, 256, 0, stream>>>(dstI, deg);
    k_offsets<<<gN, 256, 0, stream>>>(deg, dinv, rowstart, cursor, counter);
    k_fill   <<<gE, 256, 0, stream>>>(srcI, dstI, cursor, col);

    // feat = relu(LN(ext @ encW + encB))                    -> bufA
    k_gemm<1, 0, 0><<<gG, 256, 0, stream>>>(ext, nullptr, encW, encB, lng, lnb, nullptr, bufA, EXTD);
    // x = concat(emb, feat) @ projW + projB                 -> bufB
    k_gemm<0, 1, 0><<<gG, 256, 0, stream>>>(emb, bufA, projW, projB, nullptr, nullptr, nullptr, bufB, 2 * HH);
    // Z0 = dinv .* (x @ W0)                                 -> bufA
    k_gemm<0, 0, 1><<<gG, 256, 0, stream>>>(bufB, nullptr, W0, nullptr, nullptr, nullptr, dinv, bufA, HH);
    // x = relu(dinv.*(sum Z0) + b0)                         -> bufB
    k_spmm<<<gS, 256, 0, stream>>>(bufA, col, rowstart, cursor, dinv, b0, bufB, 1);
    // Z1 = dinv .* (x @ W1)                                 -> bufA
    k_gemm<0, 0, 1><<<gG, 256, 0, stream>>>(bufB, nullptr, W1, nullptr, nullptr, nullptr, dinv, bufA, HH);
    // x = relu(dinv.*(sum Z1) + b1)                         -> bufB
    k_spmm<<<gS, 256, 0, stream>>>(bufA, col, rowstart, cursor, dinv, b1, bufB, 1);
    // Z2 = dinv .* (x @ W2)                                 -> bufA
    k_gemm<0, 0, 1><<<gG, 256, 0, stream>>>(bufB, nullptr, W2, nullptr, nullptr, nullptr, dinv, bufA, HH);
    // out = dinv.*(sum Z2) + b2                             -> d_out
    k_spmm<<<gS, 256, 0, stream>>>(bufA, col, rowstart, cursor, dinv, b2, (float*)d_out, 0);
}